// Round 1
// baseline (285.178 us; speedup 1.0000x reference)
//
#include <hip/hip_runtime.h>
#include <hip/hip_bf16.h>

typedef __attribute__((ext_vector_type(8))) short bf16x8;
typedef __attribute__((ext_vector_type(4))) float f32x4;

#if defined(__has_builtin)
#if __has_builtin(__builtin_amdgcn_exp2f)
#define EXP2F(x) __builtin_amdgcn_exp2f(x)
#else
#define EXP2F(x) exp2f(x)
#endif
#else
#define EXP2F(x) exp2f(x)
#endif

#define S_LEN 2048
#define NH 32
#define HD 32
#define DMODEL 1024
#define NB 2

// ---------------------------------------------------------------------------
// Kernel 1: QKV projection. x [B,S,D] fp32 -> q,k row-major bf16 [B,H,S,d],
// v transposed bf16 [B,H,d,S]. q pre-scaled by 1/sqrt(d)*log2(e).
// grid (B*S/16, 4), block 256. Each thread owns one output column c (h,e),
// weight columns in registers, x rows broadcast from LDS.
// ---------------------------------------------------------------------------
__global__ __launch_bounds__(256) void qkv_stage(
    const float* __restrict__ x,
    const float* __restrict__ wq, const float* __restrict__ bq,
    const float* __restrict__ wk, const float* __restrict__ bk,
    const float* __restrict__ wv, const float* __restrict__ bv,
    __hip_bfloat16* __restrict__ qws,
    __hip_bfloat16* __restrict__ kws,
    __hip_bfloat16* __restrict__ vtws)
{
    const int tid = threadIdx.x;
    const int cg  = blockIdx.y;              // column group 0..3
    const int rb  = blockIdx.x;              // row block 0..255
    const int c   = cg * 256 + tid;          // global column 0..1023
    const int h   = c >> 5;
    const int e   = c & 31;
    const int row0 = rb * 16;                // global token row
    const int b   = row0 >> 11;              // /2048
    const int s0  = row0 & 2047;

    float wqc[32], wkc[32], wvc[32];
#pragma unroll
    for (int d = 0; d < 32; ++d) {
        wqc[d] = wq[d * 32 + e];
        wkc[d] = wk[d * 32 + e];
        wvc[d] = wv[d * 32 + e];
    }
    const float bqv = bq[e], bkv = bk[e], bvv = bv[e];

    __shared__ float xl[16][256];
#pragma unroll
    for (int r = 0; r < 16; ++r)
        xl[r][tid] = x[((size_t)b * S_LEN + s0 + r) * DMODEL + cg * 256 + tid];
    __syncthreads();

    const float SC = 0.1767766953f * 1.44269504089f; // 1/sqrt(32) * log2(e)
    const int hl = (tid >> 5) * 32; // local head base within the 256-col slice

    float vreg[16];
#pragma unroll
    for (int r = 0; r < 16; ++r) {
        float aq = bqv, ak = bkv, av = bvv;
#pragma unroll
        for (int d = 0; d < 32; ++d) {
            float xv = xl[r][hl + d];
            aq += xv * wqc[d];
            ak += xv * wkc[d];
            av += xv * wvc[d];
        }
        size_t base = ((size_t)(b * NH + h) * S_LEN + (s0 + r)) * HD + e;
        qws[base] = __float2bfloat16(aq * SC);
        kws[base] = __float2bfloat16(ak);
        vreg[r] = av;
    }

    // v^T write: vt[((b*H+h)*d + e)*S + s0 .. +15] as two 16B stores
    unsigned int pk[8];
#pragma unroll
    for (int i = 0; i < 8; ++i) {
        __hip_bfloat16 t0 = __float2bfloat16(vreg[2 * i]);
        __hip_bfloat16 t1 = __float2bfloat16(vreg[2 * i + 1]);
        unsigned short u0 = *reinterpret_cast<unsigned short*>(&t0);
        unsigned short u1 = *reinterpret_cast<unsigned short*>(&t1);
        pk[i] = (unsigned int)u0 | ((unsigned int)u1 << 16);
    }
    size_t vbase = ((size_t)(b * NH + h) * HD + e) * S_LEN + s0;
    uint4 lo = make_uint4(pk[0], pk[1], pk[2], pk[3]);
    uint4 hi = make_uint4(pk[4], pk[5], pk[6], pk[7]);
    *reinterpret_cast<uint4*>(vtws + vbase)     = lo;
    *reinterpret_cast<uint4*>(vtws + vbase + 8) = hi;
}

// ---------------------------------------------------------------------------
// Kernel 2: wo [K=1024][N=1024] fp32 -> wot [N][K] bf16 (padded-LDS transpose)
// grid (16,16) tiles of 64x64, block 256.
// ---------------------------------------------------------------------------
__global__ __launch_bounds__(256) void wo_transpose(
    const float* __restrict__ wo, __hip_bfloat16* __restrict__ wot)
{
    __shared__ float t[64][65];
    const int bx = blockIdx.x; // k tile
    const int by = blockIdx.y; // n tile
    const int tid = threadIdx.x;
    const int col = tid & 63, row4 = tid >> 6;
#pragma unroll
    for (int i = 0; i < 16; ++i) {
        int r = i * 4 + row4;
        t[r][col] = wo[(size_t)(bx * 64 + r) * DMODEL + by * 64 + col];
    }
    __syncthreads();
#pragma unroll
    for (int i = 0; i < 16; ++i) {
        int r = i * 4 + row4; // output n index within tile
        wot[(size_t)(by * 64 + r) * DMODEL + bx * 64 + col] =
            __float2bfloat16(t[col][r]);
    }
}

// ---------------------------------------------------------------------------
// Kernel 3: flash attention. grid = B*H*(S/64) = 2048 blocks, 256 threads.
// Wave w owns a 16-row Q strip; KVBLK=64. K/V fragments read directly from
// global (L2-resident panels). P transposed via per-wave padded LDS strip.
// ---------------------------------------------------------------------------
__global__ __launch_bounds__(256) void attn_kernel(
    const __hip_bfloat16* __restrict__ qws,
    const __hip_bfloat16* __restrict__ kws,
    const __hip_bfloat16* __restrict__ vtws,
    __hip_bfloat16* __restrict__ cws)
{
    const int tid = threadIdx.x;
    const int w  = tid >> 6;
    const int ln = tid & 63;
    const int lg = ln >> 4;   // 16-lane group 0..3
    const int lm = ln & 15;
    const int bi = blockIdx.x;
    const int qt = bi & 31;
    const int bh = bi >> 5;           // b*32 + h
    const int b  = bh >> 5;
    const int h  = bh & 31;

    const __hip_bfloat16* qp = qws  + (size_t)bh * S_LEN * HD;
    const __hip_bfloat16* kp = kws  + (size_t)bh * S_LEN * HD;
    const __hip_bfloat16* vp = vtws + (size_t)bh * HD * S_LEN;

    const int qr0 = qt * 64 + w * 16;

    // Q A-fragment: row = lm, k = lg*8 + j (d = 32 fits one MFMA K-step)
    bf16x8 qa = *reinterpret_cast<const bf16x8*>(qp + (size_t)(qr0 + lm) * HD + lg * 8);

    __shared__ __align__(16) __hip_bfloat16 plds_all[4][16][72]; // +8 bf16 pad
    __hip_bfloat16 (*plds)[72] = plds_all[w];

    float m[4]  = {-3.0e38f, -3.0e38f, -3.0e38f, -3.0e38f};
    float ls[4] = {0.f, 0.f, 0.f, 0.f};
    f32x4 o0 = {0.f, 0.f, 0.f, 0.f};
    f32x4 o1 = {0.f, 0.f, 0.f, 0.f};

    for (int kt = 0; kt < S_LEN / 64; ++kt) {
        const __hip_bfloat16* kb = kp + (size_t)kt * 64 * HD;

        // QK^T: 4 tiles of 16x16, K=32 in one MFMA each
        f32x4 s[4];
#pragma unroll
        for (int c = 0; c < 4; ++c) {
            bf16x8 kf = *reinterpret_cast<const bf16x8*>(
                kb + (size_t)(c * 16 + lm) * HD + lg * 8);
            f32x4 z = {0.f, 0.f, 0.f, 0.f};
            s[c] = __builtin_amdgcn_mfma_f32_16x16x32_bf16(qa, kf, z, 0, 0, 0);
        }

        // online softmax (base-2; q pre-scaled by 1/sqrt(d)*log2 e)
#pragma unroll
        for (int r = 0; r < 4; ++r) {
            float t = fmaxf(fmaxf(s[0][r], s[1][r]), fmaxf(s[2][r], s[3][r]));
            t = fmaxf(t, __shfl_xor(t, 1));
            t = fmaxf(t, __shfl_xor(t, 2));
            t = fmaxf(t, __shfl_xor(t, 4));
            t = fmaxf(t, __shfl_xor(t, 8));
            float newm = fmaxf(m[r], t);
            float alpha = EXP2F(m[r] - newm);
            m[r] = newm;
            float p0 = EXP2F(s[0][r] - newm);
            float p1 = EXP2F(s[1][r] - newm);
            float p2 = EXP2F(s[2][r] - newm);
            float p3 = EXP2F(s[3][r] - newm);
            float rs = (p0 + p1) + (p2 + p3);
            rs += __shfl_xor(rs, 1);
            rs += __shfl_xor(rs, 2);
            rs += __shfl_xor(rs, 4);
            rs += __shfl_xor(rs, 8);
            ls[r] = ls[r] * alpha + rs;
            o0[r] *= alpha;
            o1[r] *= alpha;
            // store P row (C-layout -> LDS strip, row-major [16][72])
            int prow = 4 * lg + r;
            plds[prow][0 * 16 + lm] = __float2bfloat16(p0);
            plds[prow][1 * 16 + lm] = __float2bfloat16(p1);
            plds[prow][2 * 16 + lm] = __float2bfloat16(p2);
            plds[prow][3 * 16 + lm] = __float2bfloat16(p3);
        }

        // PV: O[16x32] += P[16x64] * V[64x32]; A from LDS, B from V^T global
#pragma unroll
        for (int ks = 0; ks < 2; ++ks) {
            bf16x8 pa = *reinterpret_cast<const bf16x8*>(
                &plds[lm][ks * 32 + lg * 8]);
            bf16x8 v0 = *reinterpret_cast<const bf16x8*>(
                vp + (size_t)(0 * 16 + lm) * S_LEN + kt * 64 + ks * 32 + lg * 8);
            o0 = __builtin_amdgcn_mfma_f32_16x16x32_bf16(pa, v0, o0, 0, 0, 0);
            bf16x8 v1 = *reinterpret_cast<const bf16x8*>(
                vp + (size_t)(1 * 16 + lm) * S_LEN + kt * 64 + ks * 32 + lg * 8);
            o1 = __builtin_amdgcn_mfma_f32_16x16x32_bf16(pa, v1, o1, 0, 0, 0);
        }
    }

    // epilogue: normalize and write concat[b][s][h*32 + dv] as bf16
    __hip_bfloat16* cb = cws + ((size_t)b * S_LEN + qr0) * DMODEL + h * HD;
#pragma unroll
    for (int r = 0; r < 4; ++r) {
        float inv = 1.0f / ls[r];
        int row = 4 * lg + r;
        cb[(size_t)row * DMODEL + lm]      = __float2bfloat16(o0[r] * inv);
        cb[(size_t)row * DMODEL + 16 + lm] = __float2bfloat16(o1[r] * inv);
    }
}

// ---------------------------------------------------------------------------
// Kernel 4: out = concat @ wo + bo. A = concat bf16 [4096][1024],
// Bt = wot bf16 [N][K]. Wave tile 16x64, block tile 64x64, grid 1024.
// ---------------------------------------------------------------------------
__global__ __launch_bounds__(256) void out_gemm(
    const __hip_bfloat16* __restrict__ A,
    const __hip_bfloat16* __restrict__ Bt,
    const float* __restrict__ bo,
    float* __restrict__ out)
{
    const int tid = threadIdx.x;
    const int w  = tid >> 6;
    const int ln = tid & 63;
    const int lg = ln >> 4, lm = ln & 15;
    const int bi = blockIdx.x;
    const int mt = bi >> 4;   // 64 row tiles
    const int nt = bi & 15;   // 16 col tiles
    const int r0 = mt * 64 + w * 16;
    const int n0 = nt * 64;

    f32x4 acc[4] = {{0.f,0.f,0.f,0.f},{0.f,0.f,0.f,0.f},
                    {0.f,0.f,0.f,0.f},{0.f,0.f,0.f,0.f}};

    for (int k0 = 0; k0 < DMODEL; k0 += 32) {
        bf16x8 a = *reinterpret_cast<const bf16x8*>(
            A + (size_t)(r0 + lm) * DMODEL + k0 + lg * 8);
#pragma unroll
        for (int c = 0; c < 4; ++c) {
            bf16x8 bfr = *reinterpret_cast<const bf16x8*>(
                Bt + (size_t)(n0 + c * 16 + lm) * DMODEL + k0 + lg * 8);
            acc[c] = __builtin_amdgcn_mfma_f32_16x16x32_bf16(a, bfr, acc[c], 0, 0, 0);
        }
    }

#pragma unroll
    for (int c = 0; c < 4; ++c) {
        float bv = bo[n0 + c * 16 + lm];
#pragma unroll
        for (int r = 0; r < 4; ++r) {
            out[(size_t)(r0 + 4 * lg + r) * DMODEL + n0 + c * 16 + lm] =
                acc[c][r] + bv;
        }
    }
}

// ---------------------------------------------------------------------------
extern "C" void kernel_launch(void* const* d_in, const int* in_sizes, int n_in,
                              void* d_out, int out_size, void* d_ws, size_t ws_size,
                              hipStream_t stream)
{
    const float* x  = (const float*)d_in[0];
    const float* wq = (const float*)d_in[1];
    const float* bq = (const float*)d_in[2];
    const float* wk = (const float*)d_in[3];
    const float* bk = (const float*)d_in[4];
    const float* wv = (const float*)d_in[5];
    const float* bv = (const float*)d_in[6];
    const float* wo = (const float*)d_in[7];
    const float* bo = (const float*)d_in[8];
    float* out = (float*)d_out;

    char* ws = (char*)d_ws;
    __hip_bfloat16* qws  = (__hip_bfloat16*)(ws);                        // 8 MB
    __hip_bfloat16* kws  = (__hip_bfloat16*)(ws + ((size_t)8  << 20));   // 8 MB
    __hip_bfloat16* vtws = (__hip_bfloat16*)(ws + ((size_t)16 << 20));   // 8 MB
    __hip_bfloat16* cws  = (__hip_bfloat16*)(ws + ((size_t)24 << 20));   // 8 MB
    __hip_bfloat16* wot  = (__hip_bfloat16*)(ws + ((size_t)32 << 20));   // 2 MB

    qkv_stage<<<dim3(NB * S_LEN / 16, 4), 256, 0, stream>>>(
        x, wq, bq, wk, bk, wv, bv, qws, kws, vtws);
    wo_transpose<<<dim3(16, 16), 256, 0, stream>>>(wo, wot);
    attn_kernel<<<NB * NH * (S_LEN / 64), 256, 0, stream>>>(qws, kws, vtws, cws);
    out_gemm<<<(NB * S_LEN / 64) * (DMODEL / 64), 256, 0, stream>>>(
        cws, wot, bo, out);
}